// Round 1
// baseline (155.825 us; speedup 1.0000x reference)
//
#include <hip/hip_runtime.h>
#include <math.h>

#define OUT_DIM 8192
#define C_DIM   512
#define B_DIM   16
#define HW      196
#define KB      28          // K-chunk: 196 = 7*28, float4-divisible
#define NKC     7
#define BS_STRIDE 36        // 28 padded to 36 floats (144 B = 9 quads, odd -> spreads bank quads)
#define C1_CHUNK 32
#define NCHUNK  16          // 512 / 32

// ---------------------------------------------------------------------------
// K1: recover count-sketch (h, s) from the densified [512][8192] matrices.
// blockIdx.x in [0,1024): first 512 rows -> sketch1, next 512 -> sketch2.
// ---------------------------------------------------------------------------
__global__ __launch_bounds__(256) void extract_sketch(
    const float* __restrict__ S1, const float* __restrict__ S2,
    int* __restrict__ h1, float* __restrict__ s1,
    int* __restrict__ h2, float* __restrict__ s2)
{
    int bid = blockIdx.x;
    int row = bid & 511;
    const float* S = (bid < 512) ? S1 : S2;
    int* h = (bid < 512) ? h1 : h2;
    float* s = (bid < 512) ? s1 : s2;

    const float4* p = (const float4*)(S + (size_t)row * OUT_DIM);
    int t = threadIdx.x;
#pragma unroll
    for (int m = 0; m < 8; ++m) {
        int q = t + m * 256;            // float4 index, 2048 per row
        float4 v = p[q];
        int base = q * 4;
        if (v.x != 0.f) { h[row] = base + 0; s[row] = v.x; }
        if (v.y != 0.f) { h[row] = base + 1; s[row] = v.y; }
        if (v.z != 0.f) { h[row] = base + 2; s[row] = v.z; }
        if (v.w != 0.f) { h[row] = base + 3; s[row] = v.w; }
    }
}

// ---------------------------------------------------------------------------
// K2: fused Gram + count-sketch scatter.
// grid = (16 c1-chunks, 16 batches), 256 threads. One block per CU.
// Each block computes G[b, c1_base:c1_base+32, 0:512] (K=196 dot products)
// with all 512 x-rows staged in LDS per K-chunk, then scatters
// s1*s2*G into an LDS 8192-bin accumulator, writing per-chunk partials.
// ---------------------------------------------------------------------------
__global__ __launch_bounds__(256) void gram_scatter(
    const float* __restrict__ x,
    const int* __restrict__ h1, const float* __restrict__ s1,
    const int* __restrict__ h2, const float* __restrict__ s2,
    float* __restrict__ partials)
{
    __shared__ float Bs[C_DIM * BS_STRIDE];   // 512*36*4 = 73728 B
    __shared__ float bins[OUT_DIM];           // 32768 B   (total ~104 KB < 160 KB)

    const int b = blockIdx.y;
    const int chunk = blockIdx.x;
    const int c1_base = chunk * C1_CHUNK;
    const int t = threadIdx.x;
    const int tx = t & 63;                    // c2 lane: c2 = j*64 + tx
    const int ty = t >> 6;                    // c1 group: c1 = c1_base + ty*8 + i

    for (int m = t; m < OUT_DIM; m += 256) bins[m] = 0.f;

    float acc[8][8];
#pragma unroll
    for (int i = 0; i < 8; ++i)
#pragma unroll
        for (int j = 0; j < 8; ++j) acc[i][j] = 0.f;

    const float* xb = x + (size_t)b * C_DIM * HW;

    for (int kc = 0; kc < NKC; ++kc) {
        const int k0 = kc * KB;
        __syncthreads();                      // protect Bs (and bins zero on 1st iter)
        // stage all 512 rows x 28 cols: 3584 float4 units, 14 per thread
#pragma unroll
        for (int m = 0; m < 14; ++m) {
            int u = t + m * 256;
            int r = u / 7;
            int q = u - r * 7;
            float4 v = *(const float4*)(xb + r * HW + k0 + q * 4);
            *(float4*)(&Bs[r * BS_STRIDE + q * 4]) = v;
        }
        __syncthreads();
        for (int kk = 0; kk < 7; ++kk) {
            float4 a[8], bb[8];
#pragma unroll
            for (int i = 0; i < 8; ++i)       // broadcast reads (same addr per wave)
                a[i] = *(const float4*)(&Bs[(c1_base + ty * 8 + i) * BS_STRIDE + kk * 4]);
#pragma unroll
            for (int j = 0; j < 8; ++j)       // lanes spread across bank quads (stride 9 quads)
                bb[j] = *(const float4*)(&Bs[(j * 64 + tx) * BS_STRIDE + kk * 4]);
#pragma unroll
            for (int i = 0; i < 8; ++i)
#pragma unroll
                for (int j = 0; j < 8; ++j)
                    acc[i][j] += a[i].x * bb[j].x + a[i].y * bb[j].y
                               + a[i].z * bb[j].z + a[i].w * bb[j].w;
        }
    }

    // scatter: val = s1[c1]*s2[c2]*G -> bin (h1[c1]+h2[c2]) mod 8192
    int   hh1[8], hh2[8];
    float ss1[8], ss2[8];
#pragma unroll
    for (int i = 0; i < 8; ++i) {
        int c1 = c1_base + ty * 8 + i;
        hh1[i] = h1[c1]; ss1[i] = s1[c1];
    }
#pragma unroll
    for (int j = 0; j < 8; ++j) {
        int c2 = j * 64 + tx;
        hh2[j] = h2[c2]; ss2[j] = s2[c2];
    }
    __syncthreads();                          // bins fully zeroed & compute done
#pragma unroll
    for (int i = 0; i < 8; ++i)
#pragma unroll
        for (int j = 0; j < 8; ++j) {
            int bin = (hh1[i] + hh2[j]) & (OUT_DIM - 1);
            atomicAdd(&bins[bin], acc[i][j] * ss1[i] * ss2[j]);
        }
    __syncthreads();

    float* outp = partials + ((size_t)b * NCHUNK + chunk) * OUT_DIM;
    for (int m = t; m < OUT_DIM; m += 256) outp[m] = bins[m];
}

// ---------------------------------------------------------------------------
// K3: reduce 16 partials, *8192, signed sqrt, L2 normalize. One block/batch.
// ---------------------------------------------------------------------------
__global__ __launch_bounds__(256) void finalize(
    const float* __restrict__ partials, float* __restrict__ out)
{
    const int b = blockIdx.x;
    const int t = threadIdx.x;
    float xv[32];
    float ss = 0.f;
#pragma unroll
    for (int m = 0; m < 32; ++m) {
        int k = t + m * 256;
        float y = 0.f;
        for (int c = 0; c < NCHUNK; ++c)
            y += partials[((size_t)b * NCHUNK + c) * OUT_DIM + k];
        y *= (float)OUT_DIM;
        float sg = (y > 0.f) ? 1.f : ((y < 0.f) ? -1.f : 0.f);
        float v = sg * sqrtf(fabsf(y) + 1e-5f);
        xv[m] = v;
        ss += v * v;
    }
    // block reduction of sum of squares
#pragma unroll
    for (int off = 32; off; off >>= 1) ss += __shfl_down(ss, off, 64);
    __shared__ float red[4];
    if ((t & 63) == 0) red[t >> 6] = ss;
    __syncthreads();
    float tot = red[0] + red[1] + red[2] + red[3];
    float nrm = fmaxf(sqrtf(tot), 1e-12f);
    float inv = 1.f / nrm;
#pragma unroll
    for (int m = 0; m < 32; ++m)
        out[(size_t)b * OUT_DIM + t + m * 256] = xv[m] * inv;
}

// ---------------------------------------------------------------------------
extern "C" void kernel_launch(void* const* d_in, const int* in_sizes, int n_in,
                              void* d_out, int out_size, void* d_ws, size_t ws_size,
                              hipStream_t stream) {
    const float* x   = (const float*)d_in[0];
    const float* sk1 = (const float*)d_in[1];
    const float* sk2 = (const float*)d_in[2];

    char* ws = (char*)d_ws;
    int*   h1 = (int*)(ws);
    float* s1 = (float*)(ws + 2048);
    int*   h2 = (int*)(ws + 4096);
    float* s2 = (float*)(ws + 6144);
    float* partials = (float*)(ws + 8192);    // [16][16][8192] f32 = 8.39 MB

    extract_sketch<<<1024, 256, 0, stream>>>(sk1, sk2, h1, s1, h2, s2);
    gram_scatter<<<dim3(NCHUNK, B_DIM), 256, 0, stream>>>(x, h1, s1, h2, s2, partials);
    finalize<<<B_DIM, 256, 0, stream>>>(partials, (float*)d_out);
}